// Round 16
// baseline (206.926 us; speedup 1.0000x reference)
//
#include <hip/hip_runtime.h>
#include <stdint.h>

#define B_   8
#define N1_  2048
#define N2_  8192

typedef unsigned short ushort_t;
typedef __attribute__((ext_vector_type(8))) short short8;
typedef __attribute__((ext_vector_type(8))) unsigned short ushort8;
typedef __attribute__((ext_vector_type(4))) unsigned short ushort4v;
typedef __attribute__((ext_vector_type(4))) float f32x4;

__device__ __forceinline__ float b2f(unsigned short u) {
  union { unsigned int i; float f; } v;
  v.i = ((unsigned int)u) << 16;
  return v.f;
}
__device__ __forceinline__ unsigned short f2b(float f) {  // RNE bf16 round
  unsigned int x = __builtin_bit_cast(unsigned int, f);
  unsigned int r = x + 0x7FFFu + ((x >> 16) & 1u);
  return (unsigned short)(r >> 16);
}
__device__ __forceinline__ f32x4 mfma16(ushort8 a, ushort8 b, f32x4 c) {
  return __builtin_amdgcn_mfma_f32_16x16x32_bf16(
      __builtin_bit_cast(short8, a), __builtin_bit_cast(short8, b), c, 0, 0, 0);
}
__device__ __forceinline__ void gl_lds16(const void* gsrc, void* ldst) {
  __builtin_amdgcn_global_load_lds(
      (const __attribute__((address_space(1))) unsigned int*)(uintptr_t)gsrc,
      (__attribute__((address_space(3))) unsigned int*)(uint32_t)(uintptr_t)ldst,
      16, 0, 0);
}

// branchless top-3 insert into (k0<=k1<=k2, i0,i1,i2); cmps on OLD values
#define INS3(k0,k1,k2,i0,i1,i2,DD,II)                 \
  {                                                   \
    const float d_ = (DD); const int i_ = (II);       \
    const bool c0_ = d_ < k0;                         \
    const bool c1_ = d_ < k1;                         \
    const bool c2_ = d_ < k2;                         \
    i2 = c2_ ? (c1_ ? i1 : i_) : i2;                  \
    i1 = c1_ ? (c0_ ? i0 : i_) : i1;                  \
    i0 = c0_ ? i_ : i0;                               \
    k2 = __builtin_amdgcn_fmed3f(k1, k2, d_);         \
    k1 = __builtin_amdgcn_fmed3f(k0, k1, d_);         \
    k0 = fminf(k0, d_);                               \
  }

// ---- k_prep: ref 2D (64x64) bucket-sort (blocks 0..7) | feat1 T+cvt | wcvt ----
__global__ __launch_bounds__(256) void k_prep(const float* __restrict__ feat1,
                                              ushort_t* __restrict__ f1tb,
                                              const float* __restrict__ xyz1,
                                              float* __restrict__ sxg,
                                              float* __restrict__ syg,
                                              float* __restrict__ szg,
                                              unsigned* __restrict__ siog,
                                              int* __restrict__ gridg,
                                              const float* __restrict__ W1,
                                              const float* __restrict__ W2,
                                              ushort_t* __restrict__ W1b,
                                              ushort_t* __restrict__ W2b) {
  __shared__ int hist[4096];
  __shared__ int cnt[256];
  __shared__ float tl[32][33];
  const int bid = blockIdx.x, t = threadIdx.x;
  if (bid < 8) {
    // 2D counting sort by (xb,yb) 64x64; gridg[b][key] = bucket base (exact prefix)
    const int b = bid;
    const float* p1 = xyz1 + (size_t)b * 3 * N1_;
    for (int i = t; i < 4096; i += 256) hist[i] = 0;
    __syncthreads();
    int key[8]; float xv[8], yv[8];
#pragma unroll
    for (int r = 0; r < 8; ++r) {
      const int s = r * 256 + t;
      const float x = p1[s], y = p1[2048 + s];
      int kx = (int)floorf((x + 6.0f) * (64.0f / 12.0f));
      kx = kx < 0 ? 0 : (kx > 63 ? 63 : kx);
      int ky = (int)floorf((y + 6.0f) * (64.0f / 12.0f));
      ky = ky < 0 ? 0 : (ky > 63 ? 63 : ky);
      key[r] = kx * 64 + ky; xv[r] = x; yv[r] = y;
      atomicAdd(&hist[key[r]], 1);
    }
    __syncthreads();
    // 2-level exclusive prefix over 4096: thread t owns buckets [t*16, t*16+16)
    const int b16 = t * 16;
    int tmp[16]; int lsum = 0;
#pragma unroll
    for (int j = 0; j < 16; ++j) { tmp[j] = lsum; lsum += hist[b16 + j]; }
    cnt[t] = lsum;
    __syncthreads();
    for (int off = 1; off < 256; off <<= 1) {
      const int v = (t >= off) ? cnt[t - off] : 0;
      __syncthreads();
      cnt[t] += v;
      __syncthreads();
    }
    const int ex = cnt[t] - lsum;
#pragma unroll
    for (int j = 0; j < 16; ++j) {
      const int v = ex + tmp[j];
      gridg[b * 4097 + b16 + j] = v;
      hist[b16 + j] = v;                    // running scatter counters
    }
    if (t == 255) gridg[b * 4097 + 4096] = 2048;
    __syncthreads();
#pragma unroll
    for (int r = 0; r < 8; ++r) {
      const int s = r * 256 + t;
      const int pos = atomicAdd(&hist[key[r]], 1);
      sxg[b * 2048 + pos] = xv[r];
      syg[b * 2048 + pos] = yv[r];
      szg[b * 2048 + pos] = p1[4096 + s];
      siog[b * 2048 + pos] = (unsigned)s;
    }
  } else if (bid < 4104) {
    // feat1[b][256][2048] -> f1tb[(b*2048+n)][256], f32 -> bf16
    const int tt = bid - 8;
    const int cb = tt & 63, rb = (tt >> 6) & 7, b = tt >> 9;
    const int c0 = cb * 32, r0 = rb * 32;
    const int tx = t & 31, ty = t >> 5;
    const float* pin = feat1 + (size_t)b * 256 * 2048;
    ushort_t* pout = f1tb + (size_t)b * 256 * 2048;
#pragma unroll
    for (int j = 0; j < 4; ++j)
      tl[ty * 4 + j][tx] = pin[(size_t)(r0 + ty * 4 + j) * 2048 + c0 + tx];
    __syncthreads();
#pragma unroll
    for (int j = 0; j < 4; ++j)
      pout[(size_t)(c0 + ty * 4 + j) * 256 + r0 + tx] = f2b(tl[tx][ty * 4 + j]);
  } else {
    const int i = ((bid - 4104) * 256 + t) * 4;
    const float* src; ushort_t* dst; int off;
    if (i < 98304) { src = W1; dst = W1b; off = i; }
    else { off = i - 98304; if (off >= 65536) return; src = W2; dst = W2b; }
    const float4 v = *(const float4*)&src[off];
    ushort4v o;
    o[0] = f2b(v.x); o[1] = f2b(v.y); o[2] = f2b(v.z); o[3] = f2b(v.w);
    *(ushort4v*)&dst[off] = o;
  }
}

// ---- k_nn3: 2D-grid two-phase scan (pilot + non-overlapping column ranges) | t2x ----
__global__ __launch_bounds__(256) void k_nn3(const float* __restrict__ xyz2,
                                             const float* __restrict__ sxg,
                                             const float* __restrict__ syg,
                                             const float* __restrict__ szg,
                                             const unsigned* __restrict__ siog,
                                             const int* __restrict__ gridg,
                                             const ushort_t* __restrict__ f1tb,
                                             ushort_t* __restrict__ xcat,
                                             const float* __restrict__ feat2) {
  __shared__ __align__(16) float sx[2080];   // 2048 + 32 INF sentinels
  __shared__ __align__(16) float sy[2080];
  __shared__ __align__(16) float sz[2080];
  const int bid = blockIdx.x, t = threadIdx.x;

  if (bid >= 2048) {
    // feat2[b][128][8192] -> xcat[m][384] cols 256..383 (reuse sx as 32x33 tile)
    float (*tl)[33] = (float(*)[33])sx;
    const int tt = bid - 2048;
    const int n0 = (tt & 255) * 32, c0 = ((tt >> 8) & 3) * 32, b = tt >> 10;
    const int tx = t & 31, ty = t >> 5;
    const float* pin = feat2 + (size_t)b * 128 * N2_;
#pragma unroll
    for (int j = 0; j < 4; ++j)
      tl[ty * 4 + j][tx] = pin[(size_t)(c0 + ty * 4 + j) * N2_ + n0 + tx];
    __syncthreads();
    const int nr = t >> 3, cg = t & 7;
    ushort4v o;
#pragma unroll
    for (int j = 0; j < 4; ++j)
      o[j] = f2b(tl[cg * 4 + j][nr]);
    *(ushort4v*)&xcat[((size_t)b * N2_ + n0 + nr) * 384 + 256 + c0 + cg * 4] = o;
    return;
  }

  const int b = bid >> 8;              // 256 blocks per batch
  const int qb = (bid & 255) * 32;     // 32 queries per block
  for (int i = t; i < 2080; i += 256) {
    const bool v = i < 2048;
    sx[i] = v ? sxg[b * 2048 + i] : 3.4e38f;
    sy[i] = v ? syg[b * 2048 + i] : 3.4e38f;
    sz[i] = v ? szg[b * 2048 + i] : 3.4e38f;
  }
  __syncthreads();

  const int* g2 = gridg + b * 4097;    // L2-resident; few lookups per query
  const int lane = t & 63;
  const int q = t >> 3, c = t & 7;
  const int n = qb + q;
  const float px = xyz2[(size_t)b * 3 * N2_ + n];
  const float py = xyz2[(size_t)b * 3 * N2_ + N2_ + n];
  const float pz = xyz2[(size_t)b * 3 * N2_ + 2 * N2_ + n];

  // chain A (dk/ik) and chain B (ek/jk): independent dependence chains
  float dk0, dk1, dk2, ek0, ek1, ek2;
  int ik0, ik1, ik2, jk0, jk1, jk2;
  auto RESET = [&] {
    dk0 = dk1 = dk2 = 3.4e38f; ik0 = ik1 = ik2 = 0;
    ek0 = ek1 = ek2 = 3.4e38f; jk0 = jk1 = jk2 = 0;
  };
  auto SCAN = [&](int bs, int niter) {
    for (int i = 0; i < niter; ++i) {
      const int wp = bs + (i * 8 + c) * 4;          // lane-consecutive float4s
      const float4 x4 = *(const float4*)&sx[wp];
      const float4 y4 = *(const float4*)&sy[wp];
      const float4 z4 = *(const float4*)&sz[wp];
      const float dx0 = x4.x - px, dy0 = y4.x - py, dz0 = z4.x - pz;
      const float dx1 = x4.y - px, dy1 = y4.y - py, dz1 = z4.y - pz;
      const float dx2 = x4.z - px, dy2 = y4.z - py, dz2 = z4.z - pz;
      const float dx3 = x4.w - px, dy3 = y4.w - py, dz3 = z4.w - pz;
      const float d0 = fmaf(dx0, dx0, fmaf(dy0, dy0, dz0 * dz0));
      const float d1 = fmaf(dx1, dx1, fmaf(dy1, dy1, dz1 * dz1));
      const float d2 = fmaf(dx2, dx2, fmaf(dy2, dy2, dz2 * dz2));
      const float d3 = fmaf(dx3, dx3, fmaf(dy3, dy3, dz3 * dz3));
      INS3(dk0, dk1, dk2, ik0, ik1, ik2, d0, wp + 0)
      INS3(ek0, ek1, ek2, jk0, jk1, jk2, d2, wp + 2)
      INS3(dk0, dk1, dk2, ik0, ik1, ik2, d1, wp + 1)
      INS3(ek0, ek1, ek2, jk0, jk1, jk2, d3, wp + 3)
    }
  };
  auto MERGE = [&] {
    // fold chain B into chain A (strict < keeps A's earlier index on ties)
    INS3(dk0, dk1, dk2, ik0, ik1, ik2, ek0, jk0)
    INS3(dk0, dk1, dk2, ik0, ik1, ik2, ek1, jk1)
    INS3(dk0, dk1, dk2, ik0, ik1, ik2, ek2, jk2)
    // butterfly across the 8 lanes of the group
#pragma unroll
    for (int d = 1; d <= 4; d <<= 1) {
      const float r0 = __shfl_xor(dk0, d);
      const float r1 = __shfl_xor(dk1, d);
      const float r2 = __shfl_xor(dk2, d);
      const int s0 = __shfl_xor(ik0, d);
      const int s1 = __shfl_xor(ik1, d);
      const int s2 = __shfl_xor(ik2, d);
      INS3(dk0, dk1, dk2, ik0, ik1, ik2, r0, s0)
      INS3(dk0, dk1, dk2, ik0, ik1, ik2, r1, s1)
      INS3(dk0, dk1, dk2, ik0, ik1, ik2, r2, s2)
    }
  };

  // phase 1 (pilot): 64 consecutive ranks around grid[key(px,py)] -> valid dk2 bound
  const float INVD = 64.0f / 12.0f;
  int kxc = (int)floorf((px + 6.0f) * INVD);
  kxc = kxc < 0 ? 0 : (kxc > 63 ? 63 : kxc);
  int kyc = (int)floorf((py + 6.0f) * INVD);
  kyc = kyc < 0 ? 0 : (kyc > 63 ? 63 : kyc);
  int pb = (g2[kxc * 64 + kyc] - 32) & ~3;
  pb = pb < 0 ? 0 : (pb > 1984 ? 1984 : pb);
  RESET(); SCAN(pb, 2); MERGE();

  // phase 2: exact conservative 2D box [px±r]x[py±r], per-x-bucket contiguous ranges.
  // se = scan-end watermark -> ranges never overlap after rounding (no double-insert).
  const float r = sqrtf(dk2 * 1.000002f);
  int kxlo = (int)floorf((px - r + 6.0f) * INVD);
  kxlo = kxlo < 0 ? 0 : (kxlo > 63 ? 63 : kxlo);
  int kxhi = (int)floorf((px + r + 6.0f) * INVD);
  kxhi = kxhi < 0 ? 0 : (kxhi > 63 ? 63 : kxhi);
  int kylo = (int)floorf((py - r + 6.0f) * INVD);
  kylo = kylo < 0 ? 0 : (kylo > 63 ? 63 : kylo);
  int kyhi = (int)floorf((py + r + 6.0f) * INVD);
  kyhi = kyhi < 0 ? 0 : (kyhi > 63 ? 63 : kyhi);
  RESET();
  int se = 0;
  for (int xb = kxlo; xb <= kxhi; ++xb) {
    int lb = g2[xb * 64 + kylo] & ~3;
    lb = lb < se ? se : lb;
    const int ub = g2[xb * 64 + kyhi + 1];
    const int nit = ub > lb ? (ub - lb + 31) >> 5 : 0;
    SCAN(lb, nit);             // overscan = real points (superset, exact) or sentinels
    se = lb + nit * 32;
  }
  MERGE();

  // leader's (tie-correct) sorted positions -> original indices
  const int lq = lane & ~7;
  const int p0 = __shfl(ik0, lq);
  const int p1_ = __shfl(ik1, lq);
  const int p2 = __shfl(ik2, lq);
  const int i0 = (int)siog[b * 2048 + p0];
  const int i1 = (int)siog[b * 2048 + p1_];
  const int i2 = (int)siog[b * 2048 + p2];
  const float e0 = fmaxf(dk0, 1e-10f);
  const float e1 = fmaxf(dk1, 1e-10f);
  const float e2 = fmaxf(dk2, 1e-10f);
  const float v0 = 1.0f / e0, v1 = 1.0f / e1, v2 = 1.0f / e2;
  const float rs = 1.0f / (v0 + v1 + v2);
  const float w0 = v0 * rs, w1 = v1 * rs, w2 = v2 * rs;

  // fused interp: each group-thread writes its 32-channel slice of xcat row n
  const ushort_t* fb = f1tb + (size_t)b * (N1_ * 256) + c * 32;
  const ushort_t* r0p = fb + (size_t)i0 * 256;
  const ushort_t* r1p = fb + (size_t)i1 * 256;
  const ushort_t* r2p = fb + (size_t)i2 * 256;
  ushort_t* outp = xcat + ((size_t)b * N2_ + n) * 384 + c * 32;
#pragma unroll
  for (int u = 0; u < 4; ++u) {
    const ushort8 a8 = *(const ushort8*)&r0p[u * 8];
    const ushort8 b8 = *(const ushort8*)&r1p[u * 8];
    const ushort8 c8 = *(const ushort8*)&r2p[u * 8];
    ushort8 o;
#pragma unroll
    for (int jj = 0; jj < 8; ++jj)
      o[jj] = f2b(w0 * b2f(a8[jj]) + w1 * b2f(b8[jj]) + w2 * b2f(c8[jj]));
    *(ushort8*)&outp[u * 8] = o;
  }
}

// ---------------- GEMM1: y1[m][256] = xcat x W1^T, A and B via global_load_lds ------
__global__ __launch_bounds__(512, 4) void k_gemm1(
    const ushort_t* __restrict__ xcat, const ushort_t* __restrict__ Wb,
    ushort_t* __restrict__ y1, float* __restrict__ part) {
  __shared__ __align__(16) ushort_t As[2][128 * 64];
  __shared__ __align__(16) ushort_t Bs[256 * 64];
  __shared__ float sRedS[512];
  __shared__ float sRedQ[512];

  const int tid = threadIdx.x;
  const int gm0 = blockIdx.x * 128;
  const int lane = tid & 63, wv = tid >> 6;
  const int wm = wv >> 2, wn = wv & 3;
  const int la = lane & 15, qg = lane >> 4;
  const int m0 = wm * 64, o0 = wn * 64;

  f32x4 acc[4][4];
#pragma unroll
  for (int mi = 0; mi < 4; ++mi)
#pragma unroll
    for (int ni = 0; ni < 4; ++ni) acc[mi][ni] = 0.0f;

  auto STAGE_A = [&](int ch, int dst) {
#pragma unroll
    for (int i = 0; i < 2; ++i) {
      const int fc = i * 512 + tid;
      const int row = fc >> 3, p = fc & 7;
      const int cc = p ^ (row & 7);
      gl_lds16(&xcat[(size_t)(gm0 + row) * 384 + ch * 64 + cc * 8],
               &As[dst][i * 4096 + wv * 512]);
    }
  };
  auto STAGE_B = [&](int ch) {
    const int kbase = ch * 64;
#pragma unroll
    for (int i = 0; i < 4; ++i) {
      const int fc = i * 512 + tid;
      const int row = fc >> 3, p = fc & 7;
      const int cc = p ^ (row & 7);
      gl_lds16(&Wb[(size_t)row * 384 + kbase + cc * 8], &Bs[i * 4096 + wv * 512]);
    }
  };
  auto COMPUTE = [&](int src) {
#pragma unroll
    for (int ks = 0; ks < 2; ++ks) {
      ushort8 af[4], bfr[4];
#pragma unroll
      for (int mi = 0; mi < 4; ++mi) {
        const int rm = m0 + mi * 16 + la;
        af[mi] = *(const ushort8*)&As[src][rm * 64 + (((ks * 4 + qg) ^ (rm & 7))) * 8];
      }
#pragma unroll
      for (int ni = 0; ni < 4; ++ni) {
        const int ro = o0 + ni * 16 + la;
        bfr[ni] = *(const ushort8*)&Bs[ro * 64 + (((ks * 4 + qg) ^ (ro & 7))) * 8];
      }
#pragma unroll
      for (int mi = 0; mi < 4; ++mi)
#pragma unroll
        for (int ni = 0; ni < 4; ++ni)
          acc[mi][ni] = mfma16(af[mi], bfr[ni], acc[mi][ni]);
    }
  };

  STAGE_A(0, 0); STAGE_B(0);
  __syncthreads();
  int buf = 0;
  for (int ch = 0; ch < 6; ++ch) {
    if (ch < 5) STAGE_A(ch + 1, buf ^ 1);
    COMPUTE(buf);
    __syncthreads();
    if (ch < 5) { STAGE_B(ch + 1); __syncthreads(); }
    buf ^= 1;
  }

#pragma unroll
  for (int mi = 0; mi < 4; ++mi)
#pragma unroll
    for (int ni = 0; ni < 4; ++ni) {
      const int oc = o0 + ni * 16 + la;
#pragma unroll
      for (int r = 0; r < 4; ++r) {
        const int m = gm0 + m0 + mi * 16 + qg * 4 + r;
        y1[(size_t)m * 256 + oc] = f2b(acc[mi][ni][r]);
      }
    }
#pragma unroll
  for (int ni = 0; ni < 4; ++ni) {
    float s = 0.f, qq = 0.f;
#pragma unroll
    for (int mi = 0; mi < 4; ++mi)
#pragma unroll
      for (int r = 0; r < 4; ++r) {
        const float v = acc[mi][ni][r];
        s += v; qq = fmaf(v, v, qq);
      }
    s += __shfl_xor(s, 16); s += __shfl_xor(s, 32);
    qq += __shfl_xor(qq, 16); qq += __shfl_xor(qq, 32);
    if (lane < 16) {
      sRedS[wm * 256 + o0 + ni * 16 + lane] = s;
      sRedQ[wm * 256 + o0 + ni * 16 + lane] = qq;
    }
  }
  __syncthreads();
  if (tid < 256) {
    part[(size_t)blockIdx.x * 512 + tid] = sRedS[tid] + sRedS[256 + tid];
    part[(size_t)blockIdx.x * 512 + 256 + tid] = sRedQ[tid] + sRedQ[256 + tid];
  }
}

// ---------------- reduce partials -> a,c coefficients ----------------
__global__ __launch_bounds__(1024) void k_reduce(const float* __restrict__ part, int nblk,
                                                 const float* __restrict__ g,
                                                 const float* __restrict__ be,
                                                 float* __restrict__ stats) {
  __shared__ float r0[1024];
  __shared__ float r1[1024];
  const int o = threadIdx.x & 255, q = threadIdx.x >> 8;
  float s = 0.0f, sq = 0.0f;
  for (int i = q; i < nblk; i += 4) {
    s  += part[(size_t)i * 512 + o];
    sq += part[(size_t)i * 512 + 256 + o];
  }
  r0[threadIdx.x] = s; r1[threadIdx.x] = sq;
  __syncthreads();
  if (threadIdx.x < 256) {
    s  = r0[o] + r0[256 + o] + r0[512 + o] + r0[768 + o];
    sq = r1[o] + r1[256 + o] + r1[512 + o] + r1[768 + o];
    const float mean = s * (1.0f / 65536.0f);
    float var = sq * (1.0f / 65536.0f) - mean * mean;
    var = fmaxf(var, 0.0f);
    const float inv = rsqrtf(var + 1e-3f);
    const float a = g[o] * inv;
    stats[o] = a;
    stats[256 + o] = fmaf(-mean, a, be[o]);
  }
}

// ---------------- GEMM2: y2[m][256] = relu(bn(y1)) x W2^T (in-place over y1) -------
__global__ __launch_bounds__(512, 4) void k_gemm2(
    ushort_t* y1, const ushort_t* __restrict__ Wb,
    const float* __restrict__ st1, float* __restrict__ part) {
  __shared__ __align__(16) ushort_t As[2][128 * 72];
  __shared__ __align__(16) ushort_t Bs[256 * 64];
  __shared__ float sSt[512];
  __shared__ float sRedS[512];
  __shared__ float sRedQ[512];

  const int tid = threadIdx.x;
  const int gm0 = blockIdx.x * 128;
  const int lane = tid & 63, wv = tid >> 6;
  const int wm = wv >> 2, wn = wv & 3;
  const int la = lane & 15, qg = lane >> 4;
  const int m0 = wm * 64, o0 = wn * 64;
  const int ar = tid >> 3, ac = tid & 7, rb2 = ar + 64;

  if (tid < 512) sSt[tid] = st1[tid];
  __syncthreads();

  f32x4 acc[4][4];
#pragma unroll
  for (int mi = 0; mi < 4; ++mi)
#pragma unroll
    for (int ni = 0; ni < 4; ++ni) acc[mi][ni] = 0.0f;

  ushort8 g0, g3;
  auto LOAD_A = [&](int ch) {
    const size_t base = (size_t)(gm0 + ar) * 256 + ch * 64 + ac * 8;
    g0 = *(const ushort8*)&y1[base];
    g3 = *(const ushort8*)&y1[base + (size_t)64 * 256];
  };
  auto PROC_A = [&](int ch, int dst) {
    const int k0 = ch * 64 + ac * 8;
    ushort8 oa, ob;
#pragma unroll
    for (int j = 0; j < 8; ++j) {
      const float a = sSt[k0 + j], cc = sSt[256 + k0 + j];
      oa[j] = f2b(fmaxf(fmaf(b2f(g0[j]), a, cc), 0.0f));
      ob[j] = f2b(fmaxf(fmaf(b2f(g3[j]), a, cc), 0.0f));
    }
    *(ushort8*)&As[dst][ar * 72 + ac * 8] = oa;
    *(ushort8*)&As[dst][rb2 * 72 + ac * 8] = ob;
  };
  auto STAGE_B = [&](int ch) {
    const int kbase = ch * 64;
#pragma unroll
    for (int i = 0; i < 4; ++i) {
      const int fc = i * 512 + tid;
      const int row = fc >> 3, p = fc & 7;
      const int cc = p ^ (row & 7);
      gl_lds16(&Wb[(size_t)row * 256 + kbase + cc * 8], &Bs[i * 4096 + wv * 512]);
    }
  };
  auto COMPUTE = [&](int src) {
#pragma unroll
    for (int ks = 0; ks < 2; ++ks) {
      ushort8 af[4], bfr[4];
#pragma unroll
      for (int mi = 0; mi < 4; ++mi)
        af[mi] = *(const ushort8*)&As[src][(m0 + mi * 16 + la) * 72 + (ks * 4 + qg) * 8];
#pragma unroll
      for (int ni = 0; ni < 4; ++ni) {
        const int ro = o0 + ni * 16 + la;
        bfr[ni] = *(const ushort8*)&Bs[ro * 64 + (((ks * 4 + qg) ^ (ro & 7))) * 8];
      }
#pragma unroll
      for (int mi = 0; mi < 4; ++mi)
#pragma unroll
        for (int ni = 0; ni < 4; ++ni)
          acc[mi][ni] = mfma16(af[mi], bfr[ni], acc[mi][ni]);
    }
  };

  STAGE_B(0); LOAD_A(0); PROC_A(0, 0);
  __syncthreads();
  int buf = 0;
  for (int ch = 0; ch < 4; ++ch) {
    if (ch < 3) LOAD_A(ch + 1);
    COMPUTE(buf);
    __syncthreads();
    if (ch < 3) { STAGE_B(ch + 1); PROC_A(ch + 1, buf ^ 1); __syncthreads(); buf ^= 1; }
  }

#pragma unroll
  for (int mi = 0; mi < 4; ++mi)
#pragma unroll
    for (int ni = 0; ni < 4; ++ni) {
      const int oc = o0 + ni * 16 + la;
#pragma unroll
      for (int r = 0; r < 4; ++r) {
        const int m = gm0 + m0 + mi * 16 + qg * 4 + r;
        y1[(size_t)m * 256 + oc] = f2b(acc[mi][ni][r]);
      }
    }
#pragma unroll
  for (int ni = 0; ni < 4; ++ni) {
    float s = 0.f, qq = 0.f;
#pragma unroll
    for (int mi = 0; mi < 4; ++mi)
#pragma unroll
      for (int r = 0; r < 4; ++r) {
        const float v = acc[mi][ni][r];
        s += v; qq = fmaf(v, v, qq);
      }
    s += __shfl_xor(s, 16); s += __shfl_xor(s, 32);
    qq += __shfl_xor(qq, 16); qq += __shfl_xor(qq, 32);
    if (lane < 16) {
      sRedS[wm * 256 + o0 + ni * 16 + lane] = s;
      sRedQ[wm * 256 + o0 + ni * 16 + lane] = qq;
    }
  }
  __syncthreads();
  if (tid < 256) {
    part[(size_t)blockIdx.x * 512 + tid] = sRedS[tid] + sRedS[256 + tid];
    part[(size_t)blockIdx.x * 512 + 256 + tid] = sRedQ[tid] + sRedQ[256 + tid];
  }
}

// ---------------- final: BN+ReLU + transpose y2[m][o] -> out[b][o][n] (f32) --------
__global__ __launch_bounds__(256) void k_final(const ushort_t* __restrict__ y2,
                                               const float* __restrict__ st2,
                                               float* __restrict__ out) {
  __shared__ __align__(16) ushort_t tile[64 * 264];
  const int t = threadIdx.x;
  const int n0 = blockIdx.x * 64;
  const int b = blockIdx.y;
#pragma unroll
  for (int r = 0; r < 8; ++r) {
    const int id = r * 256 + t;
    const int row = id >> 5, c8 = id & 31;
    *(ushort8*)&tile[row * 264 + c8 * 8] =
        *(const ushort8*)&y2[((size_t)b * N2_ + n0 + row) * 256 + c8 * 8];
  }
  __syncthreads();
#pragma unroll
  for (int r = 0; r < 16; ++r) {
    const int id = r * 256 + t;
    const int o = id >> 4, nq = id & 15;
    const float a = st2[o], c = st2[256 + o];
    float4 v;
    v.x = fmaxf(fmaf(b2f(tile[(nq * 4 + 0) * 264 + o]), a, c), 0.0f);
    v.y = fmaxf(fmaf(b2f(tile[(nq * 4 + 1) * 264 + o]), a, c), 0.0f);
    v.z = fmaxf(fmaf(b2f(tile[(nq * 4 + 2) * 264 + o]), a, c), 0.0f);
    v.w = fmaxf(fmaf(b2f(tile[(nq * 4 + 3) * 264 + o]), a, c), 0.0f);
    *(float4*)&out[((size_t)b * 256 + o) * N2_ + n0 + nq * 4] = v;
  }
}

extern "C" void kernel_launch(void* const* d_in, const int* in_sizes, int n_in,
                              void* d_out, int out_size, void* d_ws, size_t ws_size,
                              hipStream_t stream) {
  (void)in_sizes; (void)n_in; (void)out_size; (void)ws_size;
  const float* xyz2  = (const float*)d_in[0];
  const float* xyz1  = (const float*)d_in[1];
  const float* feat2 = (const float*)d_in[2];
  const float* feat1 = (const float*)d_in[3];
  const float* W1  = (const float*)d_in[4];
  const float* g1  = (const float*)d_in[6];
  const float* be1 = (const float*)d_in[7];
  const float* W2  = (const float*)d_in[8];
  const float* g2  = (const float*)d_in[10];
  const float* be2 = (const float*)d_in[11];
  float* out = (float*)d_out;

  char* ws = (char*)d_ws;
  // y1 (33.5MB) overlays f1tb (8.4MB): f1tb dead before gemm1 writes y1
  ushort_t* y1    = (ushort_t*)(ws);               // 33,554,432
  ushort_t* f1tb  = (ushort_t*)(ws);               //  8,388,608 (prep/nn3 only)
  ushort_t* xcat  = (ushort_t*)(ws + 33554432);    // 50,331,648
  ushort_t* W1b   = (ushort_t*)(ws + 83886080);    //    196,608
  ushort_t* W2b   = (ushort_t*)(ws + 84082688);    //    131,072
  float*    part1 = (float*)(ws + 84213760);       //  1,048,576
  float*    part2 = (float*)(ws + 85262336);       //  1,048,576
  float*    st1   = (float*)(ws + 86310912);       //      2,048
  float*    st2   = (float*)(ws + 86312960);       //      2,048
  float*    sxg   = (float*)(ws + 86315008);       //     65,536
  float*    syg   = (float*)(ws + 86380544);       //     65,536
  float*    szg   = (float*)(ws + 86446080);       //     65,536
  unsigned* siog  = (unsigned*)(ws + 86511616);    //     65,536
  int*      gridg = (int*)(ws + 86577152);         //    131,104 (8 x 4097 ints)

  k_prep<<<4264, 256, 0, stream>>>(feat1, f1tb, xyz1, sxg, syg, szg, siog, gridg,
                                   W1, W2, W1b, W2b);
  k_nn3<<<10240, 256, 0, stream>>>(xyz2, sxg, syg, szg, siog, gridg, f1tb, xcat, feat2);
  k_gemm1<<<512, 512, 0, stream>>>(xcat, W1b, y1, part1);
  k_reduce<<<1, 1024, 0, stream>>>(part1, 512, g1, be1, st1);
  k_gemm2<<<512, 512, 0, stream>>>(y1, W2b, st1, part2);
  k_reduce<<<1, 1024, 0, stream>>>(part2, 512, g2, be2, st2);
  k_final<<<dim3(128, 8), 256, 0, stream>>>(y1, st2, out);
}

// Round 17
// 195.705 us; speedup vs baseline: 1.0573x; 1.0573x over previous
//
#include <hip/hip_runtime.h>
#include <stdint.h>

#define B_   8
#define N1_  2048
#define N2_  8192

typedef unsigned short ushort_t;
typedef __attribute__((ext_vector_type(8))) short short8;
typedef __attribute__((ext_vector_type(8))) unsigned short ushort8;
typedef __attribute__((ext_vector_type(4))) unsigned short ushort4v;
typedef __attribute__((ext_vector_type(4))) float f32x4;

__device__ __forceinline__ float b2f(unsigned short u) {
  union { unsigned int i; float f; } v;
  v.i = ((unsigned int)u) << 16;
  return v.f;
}
__device__ __forceinline__ unsigned short f2b(float f) {  // RNE bf16 round
  unsigned int x = __builtin_bit_cast(unsigned int, f);
  unsigned int r = x + 0x7FFFu + ((x >> 16) & 1u);
  return (unsigned short)(r >> 16);
}
__device__ __forceinline__ f32x4 mfma16(ushort8 a, ushort8 b, f32x4 c) {
  return __builtin_amdgcn_mfma_f32_16x16x32_bf16(
      __builtin_bit_cast(short8, a), __builtin_bit_cast(short8, b), c, 0, 0, 0);
}
__device__ __forceinline__ void gl_lds16(const void* gsrc, void* ldst) {
  __builtin_amdgcn_global_load_lds(
      (const __attribute__((address_space(1))) unsigned int*)(uintptr_t)gsrc,
      (__attribute__((address_space(3))) unsigned int*)(uint32_t)(uintptr_t)ldst,
      16, 0, 0);
}

// branchless top-3 insert: cmps on OLD values, dist update via med3, idx via cndmask
#define INS(DD, II)                                   \
  {                                                   \
    const float d_ = (DD); const int i_ = (II);       \
    const bool c0_ = d_ < dk0;                        \
    const bool c1_ = d_ < dk1;                        \
    const bool c2_ = d_ < dk2;                        \
    ik2 = c2_ ? (c1_ ? ik1 : i_) : ik2;               \
    ik1 = c1_ ? (c0_ ? ik0 : i_) : ik1;               \
    ik0 = c0_ ? i_ : ik0;                             \
    dk2 = __builtin_amdgcn_fmed3f(dk1, dk2, d_);      \
    dk1 = __builtin_amdgcn_fmed3f(dk0, dk1, d_);      \
    dk0 = fminf(dk0, d_);                             \
  }

// ---- k_prep: ref bucket-sort (blocks 0..7) | feat1 T+cvt | wcvt ----
__global__ __launch_bounds__(256) void k_prep(const float* __restrict__ feat1,
                                              ushort_t* __restrict__ f1tb,
                                              const float* __restrict__ xyz1,
                                              float* __restrict__ sxg,
                                              float* __restrict__ syg,
                                              float* __restrict__ szg,
                                              unsigned* __restrict__ siog,
                                              int* __restrict__ gridg,
                                              const float* __restrict__ W1,
                                              const float* __restrict__ W2,
                                              ushort_t* __restrict__ W1b,
                                              ushort_t* __restrict__ W2b) {
  __shared__ int hist[256];
  __shared__ int cnt[256];
  __shared__ float tl[32][33];
  const int bid = blockIdx.x, t = threadIdx.x;
  if (bid < 8) {
    // counting sort by x-bucket; gridg[b][k] = bucket base (== rank-grid, exact)
    const int b = bid;
    const float* p1 = xyz1 + (size_t)b * 3 * N1_;
    hist[t] = 0;
    __syncthreads();
    int bkt[8]; float xv[8];
#pragma unroll
    for (int r = 0; r < 8; ++r) {
      const int s = r * 256 + t;
      const float x = p1[s];
      int k = (int)floorf((x + 6.0f) * (256.0f / 12.0f));
      k = k < 0 ? 0 : (k > 255 ? 255 : k);
      bkt[r] = k; xv[r] = x;
      atomicAdd(&hist[k], 1);
    }
    __syncthreads();
    cnt[t] = hist[t];
    __syncthreads();
    for (int off = 1; off < 256; off <<= 1) {
      const int v = (t >= off) ? cnt[t - off] : 0;
      __syncthreads();
      cnt[t] += v;
      __syncthreads();
    }
    const int ex = cnt[t] - hist[t];          // exclusive prefix
    gridg[b * 257 + t] = ex;
    if (t == 255) gridg[b * 257 + 256] = 2048;
    __syncthreads();
    hist[t] = ex;                             // running scatter counters
    __syncthreads();
#pragma unroll
    for (int r = 0; r < 8; ++r) {
      const int s = r * 256 + t;
      const int pos = atomicAdd(&hist[bkt[r]], 1);
      sxg[b * 2048 + pos] = xv[r];
      syg[b * 2048 + pos] = p1[2048 + s];
      szg[b * 2048 + pos] = p1[4096 + s];
      siog[b * 2048 + pos] = (unsigned)s;
    }
  } else if (bid < 4104) {
    // feat1[b][256][2048] -> f1tb[(b*2048+n)][256], f32 -> bf16
    const int tt = bid - 8;
    const int cb = tt & 63, rb = (tt >> 6) & 7, b = tt >> 9;
    const int c0 = cb * 32, r0 = rb * 32;
    const int tx = t & 31, ty = t >> 5;
    const float* pin = feat1 + (size_t)b * 256 * 2048;
    ushort_t* pout = f1tb + (size_t)b * 256 * 2048;
#pragma unroll
    for (int j = 0; j < 4; ++j)
      tl[ty * 4 + j][tx] = pin[(size_t)(r0 + ty * 4 + j) * 2048 + c0 + tx];
    __syncthreads();
#pragma unroll
    for (int j = 0; j < 4; ++j)
      pout[(size_t)(c0 + ty * 4 + j) * 256 + r0 + tx] = f2b(tl[tx][ty * 4 + j]);
  } else {
    const int i = ((bid - 4104) * 256 + t) * 4;
    const float* src; ushort_t* dst; int off;
    if (i < 98304) { src = W1; dst = W1b; off = i; }
    else { off = i - 98304; if (off >= 65536) return; src = W2; dst = W2b; }
    const float4 v = *(const float4*)&src[off];
    ushort4v o;
    o[0] = f2b(v.x); o[1] = f2b(v.y); o[2] = f2b(v.z); o[3] = f2b(v.w);
    *(ushort4v*)&dst[off] = o;
  }
}

// ---- k_nn3: two-phase bucket-range scan + interp (0..2047) | feat2->xcat (2048..) ----
__global__ __launch_bounds__(256) void k_nn3(const float* __restrict__ xyz2,
                                             const float* __restrict__ sxg,
                                             const float* __restrict__ syg,
                                             const float* __restrict__ szg,
                                             const unsigned* __restrict__ siog,
                                             const int* __restrict__ gridg,
                                             const ushort_t* __restrict__ f1tb,
                                             ushort_t* __restrict__ xcat,
                                             const float* __restrict__ feat2) {
  __shared__ __align__(16) float sx[2080];   // 2048 + 32 INF sentinels
  __shared__ __align__(16) float sy[2080];
  __shared__ __align__(16) float sz[2080];
  __shared__ int sgrid[257];
  const int bid = blockIdx.x, t = threadIdx.x;

  if (bid >= 2048) {
    // feat2[b][128][8192] -> xcat[m][384] cols 256..383 (reuse sx as 32x33 tile)
    float (*tl)[33] = (float(*)[33])sx;
    const int tt = bid - 2048;
    const int n0 = (tt & 255) * 32, c0 = ((tt >> 8) & 3) * 32, b = tt >> 10;
    const int tx = t & 31, ty = t >> 5;
    const float* pin = feat2 + (size_t)b * 128 * N2_;
#pragma unroll
    for (int j = 0; j < 4; ++j)
      tl[ty * 4 + j][tx] = pin[(size_t)(c0 + ty * 4 + j) * N2_ + n0 + tx];
    __syncthreads();
    const int nr = t >> 3, cg = t & 7;
    ushort4v o;
#pragma unroll
    for (int j = 0; j < 4; ++j)
      o[j] = f2b(tl[cg * 4 + j][nr]);
    *(ushort4v*)&xcat[((size_t)b * N2_ + n0 + nr) * 384 + 256 + c0 + cg * 4] = o;
    return;
  }

  const int b = bid >> 8;              // 256 blocks per batch
  const int qb = (bid & 255) * 32;     // 32 queries per block
  for (int i = t; i < 2080; i += 256) {
    const bool v = i < 2048;
    sx[i] = v ? sxg[b * 2048 + i] : 3.4e38f;
    sy[i] = v ? syg[b * 2048 + i] : 3.4e38f;
    sz[i] = v ? szg[b * 2048 + i] : 3.4e38f;
  }
  for (int i = t; i < 257; i += 256) sgrid[i] = gridg[b * 257 + i];
  __syncthreads();

  const int lane = t & 63;
  const int q = t >> 3, c = t & 7;
  const int n = qb + q;
  const float px = xyz2[(size_t)b * 3 * N2_ + n];
  const float py = xyz2[(size_t)b * 3 * N2_ + N2_ + n];
  const float pz = xyz2[(size_t)b * 3 * N2_ + 2 * N2_ + n];

  float dk0, dk1, dk2;
  int ik0, ik1, ik2;
  auto RESET = [&] { dk0 = dk1 = dk2 = 3.4e38f; ik0 = ik1 = ik2 = 0; };
  auto SCAN = [&](int bs, int niter) {
    for (int i = 0; i < niter; ++i) {
      const int wp = bs + (i * 8 + c) * 4;          // lane-consecutive float4s
      const float4 x4 = *(const float4*)&sx[wp];
      const float4 y4 = *(const float4*)&sy[wp];
      const float4 z4 = *(const float4*)&sz[wp];
#define CAND(J, XX, YY, ZZ)                                 \
      {                                                     \
        const float dx = (XX) - px;                         \
        const float dy = (YY) - py;                         \
        const float dz = (ZZ) - pz;                         \
        const float dd = fmaf(dx, dx, fmaf(dy, dy, dz * dz)); \
        INS(dd, wp + (J))                                   \
      }
      CAND(0, x4.x, y4.x, z4.x) CAND(1, x4.y, y4.y, z4.y)
      CAND(2, x4.z, y4.z, z4.z) CAND(3, x4.w, y4.w, z4.w)
#undef CAND
    }
  };
  auto MERGE = [&] {
#pragma unroll
    for (int d = 1; d <= 4; d <<= 1) {
      const float r0 = __shfl_xor(dk0, d);
      const float r1 = __shfl_xor(dk1, d);
      const float r2 = __shfl_xor(dk2, d);
      const int s0 = __shfl_xor(ik0, d);
      const int s1 = __shfl_xor(ik1, d);
      const int s2 = __shfl_xor(ik2, d);
      INS(r0, s0) INS(r1, s1) INS(r2, s2)
    }
  };

  // phase 1 (pilot): 128 ranks near grid[bucket(px)] -> valid dk2 upper bound
  const float INVD = 256.0f / 12.0f;
  int kc = (int)floorf((px + 6.0f) * INVD);
  kc = kc < 0 ? 0 : (kc > 255 ? 255 : kc);
  int pb = (sgrid[kc] - 64) & ~3;
  pb = pb < 0 ? 0 : (pb > 1920 ? 1920 : pb);
  RESET(); SCAN(pb, 4); MERGE();

  // phase 2: exact conservative range [grid[klo], grid[khi]) (bucket-level coverage)
  const float r = sqrtf(dk2 * 1.000002f);
  int klo = (int)floorf((px - r + 6.0f) * INVD);
  klo = klo < 0 ? 0 : (klo > 255 ? 255 : klo);
  int khi = (int)ceilf((px + r + 6.0f) * INVD);
  khi = khi < 1 ? 1 : (khi > 256 ? 256 : khi);
  const int lb = sgrid[klo] & ~3;
  const int ub = sgrid[khi];
  const int nit = (ub - lb + 31) >> 5;
  RESET(); SCAN(lb, nit); MERGE();

  // leader's (tie-correct) sorted positions -> original indices
  const int lq = lane & ~7;
  const int p0 = __shfl(ik0, lq);
  const int p1_ = __shfl(ik1, lq);
  const int p2 = __shfl(ik2, lq);
  const int i0 = (int)siog[b * 2048 + p0];
  const int i1 = (int)siog[b * 2048 + p1_];
  const int i2 = (int)siog[b * 2048 + p2];
  const float e0 = fmaxf(dk0, 1e-10f);
  const float e1 = fmaxf(dk1, 1e-10f);
  const float e2 = fmaxf(dk2, 1e-10f);
  const float v0 = 1.0f / e0, v1 = 1.0f / e1, v2 = 1.0f / e2;
  const float rs = 1.0f / (v0 + v1 + v2);
  const float w0 = v0 * rs, w1 = v1 * rs, w2 = v2 * rs;

  // fused interp: each group-thread writes its 32-channel slice of xcat row n
  const ushort_t* fb = f1tb + (size_t)b * (N1_ * 256) + c * 32;
  const ushort_t* r0p = fb + (size_t)i0 * 256;
  const ushort_t* r1p = fb + (size_t)i1 * 256;
  const ushort_t* r2p = fb + (size_t)i2 * 256;
  ushort_t* outp = xcat + ((size_t)b * N2_ + n) * 384 + c * 32;
#pragma unroll
  for (int u = 0; u < 4; ++u) {
    const ushort8 a8 = *(const ushort8*)&r0p[u * 8];
    const ushort8 b8 = *(const ushort8*)&r1p[u * 8];
    const ushort8 c8 = *(const ushort8*)&r2p[u * 8];
    ushort8 o;
#pragma unroll
    for (int jj = 0; jj < 8; ++jj)
      o[jj] = f2b(w0 * b2f(a8[jj]) + w1 * b2f(b8[jj]) + w2 * b2f(c8[jj]));
    *(ushort8*)&outp[u * 8] = o;
  }
}

// ---------------- GEMM1: y1[m][256] = xcat x W1^T, A and B via global_load_lds ------
__global__ __launch_bounds__(512, 4) void k_gemm1(
    const ushort_t* __restrict__ xcat, const ushort_t* __restrict__ Wb,
    ushort_t* __restrict__ y1, float* __restrict__ part) {
  __shared__ __align__(16) ushort_t As[2][128 * 64];
  __shared__ __align__(16) ushort_t Bs[256 * 64];
  __shared__ float sRedS[512];
  __shared__ float sRedQ[512];

  const int tid = threadIdx.x;
  const int gm0 = blockIdx.x * 128;
  const int lane = tid & 63, wv = tid >> 6;
  const int wm = wv >> 2, wn = wv & 3;
  const int la = lane & 15, qg = lane >> 4;
  const int m0 = wm * 64, o0 = wn * 64;

  f32x4 acc[4][4];
#pragma unroll
  for (int mi = 0; mi < 4; ++mi)
#pragma unroll
    for (int ni = 0; ni < 4; ++ni) acc[mi][ni] = 0.0f;

  auto STAGE_A = [&](int ch, int dst) {
#pragma unroll
    for (int i = 0; i < 2; ++i) {
      const int fc = i * 512 + tid;
      const int row = fc >> 3, p = fc & 7;
      const int cc = p ^ (row & 7);
      gl_lds16(&xcat[(size_t)(gm0 + row) * 384 + ch * 64 + cc * 8],
               &As[dst][i * 4096 + wv * 512]);
    }
  };
  auto STAGE_B = [&](int ch) {
    const int kbase = ch * 64;
#pragma unroll
    for (int i = 0; i < 4; ++i) {
      const int fc = i * 512 + tid;
      const int row = fc >> 3, p = fc & 7;
      const int cc = p ^ (row & 7);
      gl_lds16(&Wb[(size_t)row * 384 + kbase + cc * 8], &Bs[i * 4096 + wv * 512]);
    }
  };
  auto COMPUTE = [&](int src) {
#pragma unroll
    for (int ks = 0; ks < 2; ++ks) {
      ushort8 af[4], bfr[4];
#pragma unroll
      for (int mi = 0; mi < 4; ++mi) {
        const int rm = m0 + mi * 16 + la;
        af[mi] = *(const ushort8*)&As[src][rm * 64 + (((ks * 4 + qg) ^ (rm & 7))) * 8];
      }
#pragma unroll
      for (int ni = 0; ni < 4; ++ni) {
        const int ro = o0 + ni * 16 + la;
        bfr[ni] = *(const ushort8*)&Bs[ro * 64 + (((ks * 4 + qg) ^ (ro & 7))) * 8];
      }
#pragma unroll
      for (int mi = 0; mi < 4; ++mi)
#pragma unroll
        for (int ni = 0; ni < 4; ++ni)
          acc[mi][ni] = mfma16(af[mi], bfr[ni], acc[mi][ni]);
    }
  };

  STAGE_A(0, 0); STAGE_B(0);
  __syncthreads();
  int buf = 0;
  for (int ch = 0; ch < 6; ++ch) {
    if (ch < 5) STAGE_A(ch + 1, buf ^ 1);
    COMPUTE(buf);
    __syncthreads();
    if (ch < 5) { STAGE_B(ch + 1); __syncthreads(); }
    buf ^= 1;
  }

#pragma unroll
  for (int mi = 0; mi < 4; ++mi)
#pragma unroll
    for (int ni = 0; ni < 4; ++ni) {
      const int oc = o0 + ni * 16 + la;
#pragma unroll
      for (int r = 0; r < 4; ++r) {
        const int m = gm0 + m0 + mi * 16 + qg * 4 + r;
        y1[(size_t)m * 256 + oc] = f2b(acc[mi][ni][r]);
      }
    }
#pragma unroll
  for (int ni = 0; ni < 4; ++ni) {
    float s = 0.f, qq = 0.f;
#pragma unroll
    for (int mi = 0; mi < 4; ++mi)
#pragma unroll
      for (int r = 0; r < 4; ++r) {
        const float v = acc[mi][ni][r];
        s += v; qq = fmaf(v, v, qq);
      }
    s += __shfl_xor(s, 16); s += __shfl_xor(s, 32);
    qq += __shfl_xor(qq, 16); qq += __shfl_xor(qq, 32);
    if (lane < 16) {
      sRedS[wm * 256 + o0 + ni * 16 + lane] = s;
      sRedQ[wm * 256 + o0 + ni * 16 + lane] = qq;
    }
  }
  __syncthreads();
  if (tid < 256) {
    part[(size_t)blockIdx.x * 512 + tid] = sRedS[tid] + sRedS[256 + tid];
    part[(size_t)blockIdx.x * 512 + 256 + tid] = sRedQ[tid] + sRedQ[256 + tid];
  }
}

// ---------------- reduce partials -> a,c coefficients ----------------
__global__ __launch_bounds__(1024) void k_reduce(const float* __restrict__ part, int nblk,
                                                 const float* __restrict__ g,
                                                 const float* __restrict__ be,
                                                 float* __restrict__ stats) {
  __shared__ float r0[1024];
  __shared__ float r1[1024];
  const int o = threadIdx.x & 255, q = threadIdx.x >> 8;
  float s = 0.0f, sq = 0.0f;
  for (int i = q; i < nblk; i += 4) {
    s  += part[(size_t)i * 512 + o];
    sq += part[(size_t)i * 512 + 256 + o];
  }
  r0[threadIdx.x] = s; r1[threadIdx.x] = sq;
  __syncthreads();
  if (threadIdx.x < 256) {
    s  = r0[o] + r0[256 + o] + r0[512 + o] + r0[768 + o];
    sq = r1[o] + r1[256 + o] + r1[512 + o] + r1[768 + o];
    const float mean = s * (1.0f / 65536.0f);
    float var = sq * (1.0f / 65536.0f) - mean * mean;
    var = fmaxf(var, 0.0f);
    const float inv = rsqrtf(var + 1e-3f);
    const float a = g[o] * inv;
    stats[o] = a;
    stats[256 + o] = fmaf(-mean, a, be[o]);
  }
}

// ---------------- GEMM2: y2[m][256] = relu(bn(y1)) x W2^T (in-place over y1) -------
__global__ __launch_bounds__(512, 4) void k_gemm2(
    ushort_t* y1, const ushort_t* __restrict__ Wb,
    const float* __restrict__ st1, float* __restrict__ part) {
  __shared__ __align__(16) ushort_t As[2][128 * 72];
  __shared__ __align__(16) ushort_t Bs[256 * 64];
  __shared__ float sSt[512];
  __shared__ float sRedS[512];
  __shared__ float sRedQ[512];

  const int tid = threadIdx.x;
  const int gm0 = blockIdx.x * 128;
  const int lane = tid & 63, wv = tid >> 6;
  const int wm = wv >> 2, wn = wv & 3;
  const int la = lane & 15, qg = lane >> 4;
  const int m0 = wm * 64, o0 = wn * 64;
  const int ar = tid >> 3, ac = tid & 7, rb2 = ar + 64;

  if (tid < 512) sSt[tid] = st1[tid];
  __syncthreads();

  f32x4 acc[4][4];
#pragma unroll
  for (int mi = 0; mi < 4; ++mi)
#pragma unroll
    for (int ni = 0; ni < 4; ++ni) acc[mi][ni] = 0.0f;

  ushort8 g0, g3;
  auto LOAD_A = [&](int ch) {
    const size_t base = (size_t)(gm0 + ar) * 256 + ch * 64 + ac * 8;
    g0 = *(const ushort8*)&y1[base];
    g3 = *(const ushort8*)&y1[base + (size_t)64 * 256];
  };
  auto PROC_A = [&](int ch, int dst) {
    const int k0 = ch * 64 + ac * 8;
    ushort8 oa, ob;
#pragma unroll
    for (int j = 0; j < 8; ++j) {
      const float a = sSt[k0 + j], cc = sSt[256 + k0 + j];
      oa[j] = f2b(fmaxf(fmaf(b2f(g0[j]), a, cc), 0.0f));
      ob[j] = f2b(fmaxf(fmaf(b2f(g3[j]), a, cc), 0.0f));
    }
    *(ushort8*)&As[dst][ar * 72 + ac * 8] = oa;
    *(ushort8*)&As[dst][rb2 * 72 + ac * 8] = ob;
  };
  auto STAGE_B = [&](int ch) {
    const int kbase = ch * 64;
#pragma unroll
    for (int i = 0; i < 4; ++i) {
      const int fc = i * 512 + tid;
      const int row = fc >> 3, p = fc & 7;
      const int cc = p ^ (row & 7);
      gl_lds16(&Wb[(size_t)row * 256 + kbase + cc * 8], &Bs[i * 4096 + wv * 512]);
    }
  };
  auto COMPUTE = [&](int src) {
#pragma unroll
    for (int ks = 0; ks < 2; ++ks) {
      ushort8 af[4], bfr[4];
#pragma unroll
      for (int mi = 0; mi < 4; ++mi)
        af[mi] = *(const ushort8*)&As[src][(m0 + mi * 16 + la) * 72 + (ks * 4 + qg) * 8];
#pragma unroll
      for (int ni = 0; ni < 4; ++ni) {
        const int ro = o0 + ni * 16 + la;
        bfr[ni] = *(const ushort8*)&Bs[ro * 64 + (((ks * 4 + qg) ^ (ro & 7))) * 8];
      }
#pragma unroll
      for (int mi = 0; mi < 4; ++mi)
#pragma unroll
        for (int ni = 0; ni < 4; ++ni)
          acc[mi][ni] = mfma16(af[mi], bfr[ni], acc[mi][ni]);
    }
  };

  STAGE_B(0); LOAD_A(0); PROC_A(0, 0);
  __syncthreads();
  int buf = 0;
  for (int ch = 0; ch < 4; ++ch) {
    if (ch < 3) LOAD_A(ch + 1);
    COMPUTE(buf);
    __syncthreads();
    if (ch < 3) { STAGE_B(ch + 1); PROC_A(ch + 1, buf ^ 1); __syncthreads(); buf ^= 1; }
  }

#pragma unroll
  for (int mi = 0; mi < 4; ++mi)
#pragma unroll
    for (int ni = 0; ni < 4; ++ni) {
      const int oc = o0 + ni * 16 + la;
#pragma unroll
      for (int r = 0; r < 4; ++r) {
        const int m = gm0 + m0 + mi * 16 + qg * 4 + r;
        y1[(size_t)m * 256 + oc] = f2b(acc[mi][ni][r]);
      }
    }
#pragma unroll
  for (int ni = 0; ni < 4; ++ni) {
    float s = 0.f, qq = 0.f;
#pragma unroll
    for (int mi = 0; mi < 4; ++mi)
#pragma unroll
      for (int r = 0; r < 4; ++r) {
        const float v = acc[mi][ni][r];
        s += v; qq = fmaf(v, v, qq);
      }
    s += __shfl_xor(s, 16); s += __shfl_xor(s, 32);
    qq += __shfl_xor(qq, 16); qq += __shfl_xor(qq, 32);
    if (lane < 16) {
      sRedS[wm * 256 + o0 + ni * 16 + lane] = s;
      sRedQ[wm * 256 + o0 + ni * 16 + lane] = qq;
    }
  }
  __syncthreads();
  if (tid < 256) {
    part[(size_t)blockIdx.x * 512 + tid] = sRedS[tid] + sRedS[256 + tid];
    part[(size_t)blockIdx.x * 512 + 256 + tid] = sRedQ[tid] + sRedQ[256 + tid];
  }
}

// ---------------- final: BN+ReLU + transpose y2[m][o] -> out[b][o][n] (f32) --------
__global__ __launch_bounds__(256) void k_final(const ushort_t* __restrict__ y2,
                                               const float* __restrict__ st2,
                                               float* __restrict__ out) {
  __shared__ __align__(16) ushort_t tile[64 * 264];
  const int t = threadIdx.x;
  const int n0 = blockIdx.x * 64;
  const int b = blockIdx.y;
#pragma unroll
  for (int r = 0; r < 8; ++r) {
    const int id = r * 256 + t;
    const int row = id >> 5, c8 = id & 31;
    *(ushort8*)&tile[row * 264 + c8 * 8] =
        *(const ushort8*)&y2[((size_t)b * N2_ + n0 + row) * 256 + c8 * 8];
  }
  __syncthreads();
#pragma unroll
  for (int r = 0; r < 16; ++r) {
    const int id = r * 256 + t;
    const int o = id >> 4, nq = id & 15;
    const float a = st2[o], c = st2[256 + o];
    float4 v;
    v.x = fmaxf(fmaf(b2f(tile[(nq * 4 + 0) * 264 + o]), a, c), 0.0f);
    v.y = fmaxf(fmaf(b2f(tile[(nq * 4 + 1) * 264 + o]), a, c), 0.0f);
    v.z = fmaxf(fmaf(b2f(tile[(nq * 4 + 2) * 264 + o]), a, c), 0.0f);
    v.w = fmaxf(fmaf(b2f(tile[(nq * 4 + 3) * 264 + o]), a, c), 0.0f);
    *(float4*)&out[((size_t)b * 256 + o) * N2_ + n0 + nq * 4] = v;
  }
}

extern "C" void kernel_launch(void* const* d_in, const int* in_sizes, int n_in,
                              void* d_out, int out_size, void* d_ws, size_t ws_size,
                              hipStream_t stream) {
  (void)in_sizes; (void)n_in; (void)out_size; (void)ws_size;
  const float* xyz2  = (const float*)d_in[0];
  const float* xyz1  = (const float*)d_in[1];
  const float* feat2 = (const float*)d_in[2];
  const float* feat1 = (const float*)d_in[3];
  const float* W1  = (const float*)d_in[4];
  const float* g1  = (const float*)d_in[6];
  const float* be1 = (const float*)d_in[7];
  const float* W2  = (const float*)d_in[8];
  const float* g2  = (const float*)d_in[10];
  const float* be2 = (const float*)d_in[11];
  float* out = (float*)d_out;

  char* ws = (char*)d_ws;
  // y1 (33.5MB) overlays f1tb (8.4MB): f1tb dead before gemm1 writes y1
  ushort_t* y1    = (ushort_t*)(ws);               // 33,554,432
  ushort_t* f1tb  = (ushort_t*)(ws);               //  8,388,608 (prep/nn3 only)
  ushort_t* xcat  = (ushort_t*)(ws + 33554432);    // 50,331,648
  ushort_t* W1b   = (ushort_t*)(ws + 83886080);    //    196,608
  ushort_t* W2b   = (ushort_t*)(ws + 84082688);    //    131,072
  float*    part1 = (float*)(ws + 84213760);       //  1,048,576
  float*    part2 = (float*)(ws + 85262336);       //  1,048,576
  float*    st1   = (float*)(ws + 86310912);       //      2,048
  float*    st2   = (float*)(ws + 86312960);       //      2,048
  float*    sxg   = (float*)(ws + 86315008);       //     65,536
  float*    syg   = (float*)(ws + 86380544);       //     65,536
  float*    szg   = (float*)(ws + 86446080);       //     65,536
  unsigned* siog  = (unsigned*)(ws + 86511616);    //     65,536
  int*      gridg = (int*)(ws + 86577152);         //      8,224

  k_prep<<<4264, 256, 0, stream>>>(feat1, f1tb, xyz1, sxg, syg, szg, siog, gridg,
                                   W1, W2, W1b, W2b);
  k_nn3<<<10240, 256, 0, stream>>>(xyz2, sxg, syg, szg, siog, gridg, f1tb, xcat, feat2);
  k_gemm1<<<512, 512, 0, stream>>>(xcat, W1b, y1, part1);
  k_reduce<<<1, 1024, 0, stream>>>(part1, 512, g1, be1, st1);
  k_gemm2<<<512, 512, 0, stream>>>(y1, W2b, st1, part2);
  k_reduce<<<1, 1024, 0, stream>>>(part2, 512, g2, be2, st2);
  k_final<<<dim3(128, 8), 256, 0, stream>>>(y1, st2, out);
}

// Round 18
// 139.245 us; speedup vs baseline: 1.4861x; 1.4055x over previous
//
#include <hip/hip_runtime.h>
#include <stdint.h>

#define B_   8
#define N1_  2048
#define N2_  8192

typedef unsigned short ushort_t;
typedef __attribute__((ext_vector_type(8))) short short8;
typedef __attribute__((ext_vector_type(8))) unsigned short ushort8;
typedef __attribute__((ext_vector_type(4))) unsigned short ushort4v;
typedef __attribute__((ext_vector_type(4))) float f32x4;

__device__ __forceinline__ float b2f(unsigned short u) {
  union { unsigned int i; float f; } v;
  v.i = ((unsigned int)u) << 16;
  return v.f;
}
__device__ __forceinline__ unsigned short f2b(float f) {  // RNE bf16 round
  unsigned int x = __builtin_bit_cast(unsigned int, f);
  unsigned int r = x + 0x7FFFu + ((x >> 16) & 1u);
  return (unsigned short)(r >> 16);
}
__device__ __forceinline__ f32x4 mfma16(ushort8 a, ushort8 b, f32x4 c) {
  return __builtin_amdgcn_mfma_f32_16x16x32_bf16(
      __builtin_bit_cast(short8, a), __builtin_bit_cast(short8, b), c, 0, 0, 0);
}
__device__ __forceinline__ void gl_lds16(const void* gsrc, void* ldst) {
  __builtin_amdgcn_global_load_lds(
      (const __attribute__((address_space(1))) unsigned int*)(uintptr_t)gsrc,
      (__attribute__((address_space(3))) unsigned int*)(uint32_t)(uintptr_t)ldst,
      16, 0, 0);
}

// branchless top-3 insert: cmps on OLD values, dist update via med3, idx via cndmask
#define INS(DD, II)                                   \
  {                                                   \
    const float d_ = (DD); const int i_ = (II);       \
    const bool c0_ = d_ < dk0;                        \
    const bool c1_ = d_ < dk1;                        \
    const bool c2_ = d_ < dk2;                        \
    ik2 = c2_ ? (c1_ ? ik1 : i_) : ik2;               \
    ik1 = c1_ ? (c0_ ? ik0 : i_) : ik1;               \
    ik0 = c0_ ? i_ : ik0;                             \
    dk2 = __builtin_amdgcn_fmed3f(dk1, dk2, d_);      \
    dk1 = __builtin_amdgcn_fmed3f(dk0, dk1, d_);      \
    dk0 = fminf(dk0, d_);                             \
  }

// ---- k_prep: ref bucket-sort (blocks 0..7) | feat1 T+cvt | wcvt ----
__global__ __launch_bounds__(256) void k_prep(const float* __restrict__ feat1,
                                              ushort_t* __restrict__ f1tb,
                                              const float* __restrict__ xyz1,
                                              float* __restrict__ sxg,
                                              float* __restrict__ syg,
                                              float* __restrict__ szg,
                                              unsigned* __restrict__ siog,
                                              int* __restrict__ gridg,
                                              const float* __restrict__ W1,
                                              const float* __restrict__ W2,
                                              ushort_t* __restrict__ W1b,
                                              ushort_t* __restrict__ W2b) {
  __shared__ int hist[256];
  __shared__ int cnt[256];
  __shared__ float tl[32][33];
  const int bid = blockIdx.x, t = threadIdx.x;
  if (bid < 8) {
    // counting sort by x-bucket; gridg[b][k] = bucket base (== rank-grid, exact)
    const int b = bid;
    const float* p1 = xyz1 + (size_t)b * 3 * N1_;
    hist[t] = 0;
    __syncthreads();
    int bkt[8]; float xv[8];
#pragma unroll
    for (int r = 0; r < 8; ++r) {
      const int s = r * 256 + t;
      const float x = p1[s];
      int k = (int)floorf((x + 6.0f) * (256.0f / 12.0f));
      k = k < 0 ? 0 : (k > 255 ? 255 : k);
      bkt[r] = k; xv[r] = x;
      atomicAdd(&hist[k], 1);
    }
    __syncthreads();
    cnt[t] = hist[t];
    __syncthreads();
    for (int off = 1; off < 256; off <<= 1) {
      const int v = (t >= off) ? cnt[t - off] : 0;
      __syncthreads();
      cnt[t] += v;
      __syncthreads();
    }
    const int ex = cnt[t] - hist[t];          // exclusive prefix
    gridg[b * 257 + t] = ex;
    if (t == 255) gridg[b * 257 + 256] = 2048;
    __syncthreads();
    hist[t] = ex;                             // running scatter counters
    __syncthreads();
#pragma unroll
    for (int r = 0; r < 8; ++r) {
      const int s = r * 256 + t;
      const int pos = atomicAdd(&hist[bkt[r]], 1);
      sxg[b * 2048 + pos] = xv[r];
      syg[b * 2048 + pos] = p1[2048 + s];
      szg[b * 2048 + pos] = p1[4096 + s];
      siog[b * 2048 + pos] = (unsigned)s;
    }
  } else if (bid < 4104) {
    // feat1[b][256][2048] -> f1tb[(b*2048+n)][256], f32 -> bf16
    const int tt = bid - 8;
    const int cb = tt & 63, rb = (tt >> 6) & 7, b = tt >> 9;
    const int c0 = cb * 32, r0 = rb * 32;
    const int tx = t & 31, ty = t >> 5;
    const float* pin = feat1 + (size_t)b * 256 * 2048;
    ushort_t* pout = f1tb + (size_t)b * 256 * 2048;
#pragma unroll
    for (int j = 0; j < 4; ++j)
      tl[ty * 4 + j][tx] = pin[(size_t)(r0 + ty * 4 + j) * 2048 + c0 + tx];
    __syncthreads();
#pragma unroll
    for (int j = 0; j < 4; ++j)
      pout[(size_t)(c0 + ty * 4 + j) * 256 + r0 + tx] = f2b(tl[tx][ty * 4 + j]);
  } else {
    const int i = ((bid - 4104) * 256 + t) * 4;
    const float* src; ushort_t* dst; int off;
    if (i < 98304) { src = W1; dst = W1b; off = i; }
    else { off = i - 98304; if (off >= 65536) return; src = W2; dst = W2b; }
    const float4 v = *(const float4*)&src[off];
    ushort4v o;
    o[0] = f2b(v.x); o[1] = f2b(v.y); o[2] = f2b(v.z); o[3] = f2b(v.w);
    *(ushort4v*)&dst[off] = o;
  }
}

// ---- k_nn3: two-phase bucket-range scan + interp (0..2047) | feat2->xcat (2048..) ----
__global__ __launch_bounds__(256) void k_nn3(const float* __restrict__ xyz2,
                                             const float* __restrict__ sxg,
                                             const float* __restrict__ syg,
                                             const float* __restrict__ szg,
                                             const unsigned* __restrict__ siog,
                                             const int* __restrict__ gridg,
                                             const ushort_t* __restrict__ f1tb,
                                             ushort_t* __restrict__ xcat,
                                             const float* __restrict__ feat2) {
  __shared__ __align__(16) float sx[2080];   // 2048 + 32 INF sentinels
  __shared__ __align__(16) float sy[2080];
  __shared__ __align__(16) float sz[2080];
  __shared__ int sgrid[257];
  const int bid = blockIdx.x, t = threadIdx.x;

  if (bid >= 2048) {
    // feat2[b][128][8192] -> xcat[m][384] cols 256..383 (reuse sx as 32x33 tile)
    float (*tl)[33] = (float(*)[33])sx;
    const int tt = bid - 2048;
    const int n0 = (tt & 255) * 32, c0 = ((tt >> 8) & 3) * 32, b = tt >> 10;
    const int tx = t & 31, ty = t >> 5;
    const float* pin = feat2 + (size_t)b * 128 * N2_;
#pragma unroll
    for (int j = 0; j < 4; ++j)
      tl[ty * 4 + j][tx] = pin[(size_t)(c0 + ty * 4 + j) * N2_ + n0 + tx];
    __syncthreads();
    const int nr = t >> 3, cg = t & 7;
    ushort4v o;
#pragma unroll
    for (int j = 0; j < 4; ++j)
      o[j] = f2b(tl[cg * 4 + j][nr]);
    *(ushort4v*)&xcat[((size_t)b * N2_ + n0 + nr) * 384 + 256 + c0 + cg * 4] = o;
    return;
  }

  const int b = bid >> 8;              // 256 blocks per batch
  const int qb = (bid & 255) * 32;     // 32 queries per block
  for (int i = t; i < 2080; i += 256) {
    const bool v = i < 2048;
    sx[i] = v ? sxg[b * 2048 + i] : 3.4e38f;
    sy[i] = v ? syg[b * 2048 + i] : 3.4e38f;
    sz[i] = v ? szg[b * 2048 + i] : 3.4e38f;
  }
  for (int i = t; i < 257; i += 256) sgrid[i] = gridg[b * 257 + i];
  __syncthreads();

  const int lane = t & 63;
  const int q = t >> 3, c = t & 7;
  const int n = qb + q;
  const float px = xyz2[(size_t)b * 3 * N2_ + n];
  const float py = xyz2[(size_t)b * 3 * N2_ + N2_ + n];
  const float pz = xyz2[(size_t)b * 3 * N2_ + 2 * N2_ + n];

  float dk0, dk1, dk2;
  int ik0, ik1, ik2;
  auto RESET = [&] { dk0 = dk1 = dk2 = 3.4e38f; ik0 = ik1 = ik2 = 0; };
  auto SCAN = [&](int bs, int niter) {
    for (int i = 0; i < niter; ++i) {
      const int wp = bs + (i * 8 + c) * 4;          // lane-consecutive float4s
      const float4 x4 = *(const float4*)&sx[wp];
      const float4 y4 = *(const float4*)&sy[wp];
      const float4 z4 = *(const float4*)&sz[wp];
#define CAND(J, XX, YY, ZZ)                                 \
      {                                                     \
        const float dx = (XX) - px;                         \
        const float dy = (YY) - py;                         \
        const float dz = (ZZ) - pz;                         \
        const float dd = fmaf(dx, dx, fmaf(dy, dy, dz * dz)); \
        INS(dd, wp + (J))                                   \
      }
      CAND(0, x4.x, y4.x, z4.x) CAND(1, x4.y, y4.y, z4.y)
      CAND(2, x4.z, y4.z, z4.z) CAND(3, x4.w, y4.w, z4.w)
#undef CAND
    }
  };
  auto MERGE = [&] {
#pragma unroll
    for (int d = 1; d <= 4; d <<= 1) {
      const float r0 = __shfl_xor(dk0, d);
      const float r1 = __shfl_xor(dk1, d);
      const float r2 = __shfl_xor(dk2, d);
      const int s0 = __shfl_xor(ik0, d);
      const int s1 = __shfl_xor(ik1, d);
      const int s2 = __shfl_xor(ik2, d);
      INS(r0, s0) INS(r1, s1) INS(r2, s2)
    }
  };

  // phase 1 (pilot): 128 ranks near grid[bucket(px)] -> valid dk2 upper bound
  const float INVD = 256.0f / 12.0f;
  int kc = (int)floorf((px + 6.0f) * INVD);
  kc = kc < 0 ? 0 : (kc > 255 ? 255 : kc);
  int pb = (sgrid[kc] - 64) & ~3;
  pb = pb < 0 ? 0 : (pb > 1920 ? 1920 : pb);
  RESET(); SCAN(pb, 4); MERGE();

  // phase 2: exact conservative range [grid[klo], grid[khi]) (bucket-level coverage)
  const float r = sqrtf(dk2 * 1.000002f);
  int klo = (int)floorf((px - r + 6.0f) * INVD);
  klo = klo < 0 ? 0 : (klo > 255 ? 255 : klo);
  int khi = (int)ceilf((px + r + 6.0f) * INVD);
  khi = khi < 1 ? 1 : (khi > 256 ? 256 : khi);
  const int lb = sgrid[klo] & ~3;
  const int ub = sgrid[khi];
  const int nit = (ub - lb + 31) >> 5;
  RESET(); SCAN(lb, nit); MERGE();

  // leader's (tie-correct) sorted positions -> original indices
  const int lq = lane & ~7;
  const int p0 = __shfl(ik0, lq);
  const int p1_ = __shfl(ik1, lq);
  const int p2 = __shfl(ik2, lq);
  const int i0 = (int)siog[b * 2048 + p0];
  const int i1 = (int)siog[b * 2048 + p1_];
  const int i2 = (int)siog[b * 2048 + p2];
  const float e0 = fmaxf(dk0, 1e-10f);
  const float e1 = fmaxf(dk1, 1e-10f);
  const float e2 = fmaxf(dk2, 1e-10f);
  const float v0 = 1.0f / e0, v1 = 1.0f / e1, v2 = 1.0f / e2;
  const float rs = 1.0f / (v0 + v1 + v2);
  const float w0 = v0 * rs, w1 = v1 * rs, w2 = v2 * rs;

  // fused interp: each group-thread writes its 32-channel slice of xcat row n
  const ushort_t* fb = f1tb + (size_t)b * (N1_ * 256) + c * 32;
  const ushort_t* r0p = fb + (size_t)i0 * 256;
  const ushort_t* r1p = fb + (size_t)i1 * 256;
  const ushort_t* r2p = fb + (size_t)i2 * 256;
  ushort_t* outp = xcat + ((size_t)b * N2_ + n) * 384 + c * 32;
#pragma unroll
  for (int u = 0; u < 4; ++u) {
    const ushort8 a8 = *(const ushort8*)&r0p[u * 8];
    const ushort8 b8 = *(const ushort8*)&r1p[u * 8];
    const ushort8 c8 = *(const ushort8*)&r2p[u * 8];
    ushort8 o;
#pragma unroll
    for (int jj = 0; jj < 8; ++jj)
      o[jj] = f2b(w0 * b2f(a8[jj]) + w1 * b2f(b8[jj]) + w2 * b2f(c8[jj]));
    *(ushort8*)&outp[u * 8] = o;
  }
}

// ---------------- GEMM1: y1[m][256] = xcat x W1^T, A and B via global_load_lds ------
__global__ __launch_bounds__(512, 4) void k_gemm1(
    const ushort_t* __restrict__ xcat, const ushort_t* __restrict__ Wb,
    ushort_t* __restrict__ y1, float* __restrict__ part) {
  __shared__ __align__(16) ushort_t As[2][128 * 64];
  __shared__ __align__(16) ushort_t Bs[256 * 64];
  __shared__ float sRedS[512];
  __shared__ float sRedQ[512];

  const int tid = threadIdx.x;
  const int gm0 = blockIdx.x * 128;
  const int lane = tid & 63, wv = tid >> 6;
  const int wm = wv >> 2, wn = wv & 3;
  const int la = lane & 15, qg = lane >> 4;
  const int m0 = wm * 64, o0 = wn * 64;

  f32x4 acc[4][4];
#pragma unroll
  for (int mi = 0; mi < 4; ++mi)
#pragma unroll
    for (int ni = 0; ni < 4; ++ni) acc[mi][ni] = 0.0f;

  auto STAGE_A = [&](int ch, int dst) {
#pragma unroll
    for (int i = 0; i < 2; ++i) {
      const int fc = i * 512 + tid;
      const int row = fc >> 3, p = fc & 7;
      const int cc = p ^ (row & 7);
      gl_lds16(&xcat[(size_t)(gm0 + row) * 384 + ch * 64 + cc * 8],
               &As[dst][i * 4096 + wv * 512]);
    }
  };
  auto STAGE_B = [&](int ch) {
    const int kbase = ch * 64;
#pragma unroll
    for (int i = 0; i < 4; ++i) {
      const int fc = i * 512 + tid;
      const int row = fc >> 3, p = fc & 7;
      const int cc = p ^ (row & 7);
      gl_lds16(&Wb[(size_t)row * 384 + kbase + cc * 8], &Bs[i * 4096 + wv * 512]);
    }
  };
  auto COMPUTE = [&](int src) {
#pragma unroll
    for (int ks = 0; ks < 2; ++ks) {
      ushort8 af[4], bfr[4];
#pragma unroll
      for (int mi = 0; mi < 4; ++mi) {
        const int rm = m0 + mi * 16 + la;
        af[mi] = *(const ushort8*)&As[src][rm * 64 + (((ks * 4 + qg) ^ (rm & 7))) * 8];
      }
#pragma unroll
      for (int ni = 0; ni < 4; ++ni) {
        const int ro = o0 + ni * 16 + la;
        bfr[ni] = *(const ushort8*)&Bs[ro * 64 + (((ks * 4 + qg) ^ (ro & 7))) * 8];
      }
#pragma unroll
      for (int mi = 0; mi < 4; ++mi)
#pragma unroll
        for (int ni = 0; ni < 4; ++ni)
          acc[mi][ni] = mfma16(af[mi], bfr[ni], acc[mi][ni]);
    }
  };

  STAGE_A(0, 0); STAGE_B(0);
  __syncthreads();
  int buf = 0;
  for (int ch = 0; ch < 6; ++ch) {
    if (ch < 5) STAGE_A(ch + 1, buf ^ 1);
    COMPUTE(buf);
    __syncthreads();
    if (ch < 5) { STAGE_B(ch + 1); __syncthreads(); }
    buf ^= 1;
  }

#pragma unroll
  for (int mi = 0; mi < 4; ++mi)
#pragma unroll
    for (int ni = 0; ni < 4; ++ni) {
      const int oc = o0 + ni * 16 + la;
#pragma unroll
      for (int r = 0; r < 4; ++r) {
        const int m = gm0 + m0 + mi * 16 + qg * 4 + r;
        y1[(size_t)m * 256 + oc] = f2b(acc[mi][ni][r]);
      }
    }
#pragma unroll
  for (int ni = 0; ni < 4; ++ni) {
    float s = 0.f, qq = 0.f;
#pragma unroll
    for (int mi = 0; mi < 4; ++mi)
#pragma unroll
      for (int r = 0; r < 4; ++r) {
        const float v = acc[mi][ni][r];
        s += v; qq = fmaf(v, v, qq);
      }
    s += __shfl_xor(s, 16); s += __shfl_xor(s, 32);
    qq += __shfl_xor(qq, 16); qq += __shfl_xor(qq, 32);
    if (lane < 16) {
      sRedS[wm * 256 + o0 + ni * 16 + lane] = s;
      sRedQ[wm * 256 + o0 + ni * 16 + lane] = qq;
    }
  }
  __syncthreads();
  if (tid < 256) {
    part[(size_t)blockIdx.x * 512 + tid] = sRedS[tid] + sRedS[256 + tid];
    part[(size_t)blockIdx.x * 512 + 256 + tid] = sRedQ[tid] + sRedQ[256 + tid];
  }
}

// ---- reduce partials -> a,c coefficients (256 blocks, one channel each) ----
__global__ __launch_bounds__(256) void k_reduce(const float* __restrict__ part,
                                                const float* __restrict__ g,
                                                const float* __restrict__ be,
                                                float* __restrict__ stats) {
  __shared__ float r0[256];
  __shared__ float r1[256];
  const int o = blockIdx.x, t = threadIdx.x;
  float s  = part[(size_t)t * 512 + o]       + part[(size_t)(t + 256) * 512 + o];
  float sq = part[(size_t)t * 512 + 256 + o] + part[(size_t)(t + 256) * 512 + 256 + o];
  r0[t] = s; r1[t] = sq;
  __syncthreads();
  for (int off = 128; off >= 1; off >>= 1) {
    if (t < off) { r0[t] += r0[t + off]; r1[t] += r1[t + off]; }
    __syncthreads();
  }
  if (t == 0) {
    const float mean = r0[0] * (1.0f / 65536.0f);
    float var = r1[0] * (1.0f / 65536.0f) - mean * mean;
    var = fmaxf(var, 0.0f);
    const float inv = rsqrtf(var + 1e-3f);
    const float a = g[o] * inv;
    stats[o] = a;
    stats[256 + o] = fmaf(-mean, a, be[o]);
  }
}

// ---------------- GEMM2: y2[m][256] = relu(bn(y1)) x W2^T (in-place over y1) -------
__global__ __launch_bounds__(512, 4) void k_gemm2(
    ushort_t* y1, const ushort_t* __restrict__ Wb,
    const float* __restrict__ st1, float* __restrict__ part) {
  __shared__ __align__(16) ushort_t As[2][128 * 72];
  __shared__ __align__(16) ushort_t Bs[256 * 64];
  __shared__ float sSt[512];
  __shared__ float sRedS[512];
  __shared__ float sRedQ[512];

  const int tid = threadIdx.x;
  const int gm0 = blockIdx.x * 128;
  const int lane = tid & 63, wv = tid >> 6;
  const int wm = wv >> 2, wn = wv & 3;
  const int la = lane & 15, qg = lane >> 4;
  const int m0 = wm * 64, o0 = wn * 64;
  const int ar = tid >> 3, ac = tid & 7, rb2 = ar + 64;

  if (tid < 512) sSt[tid] = st1[tid];
  __syncthreads();

  f32x4 acc[4][4];
#pragma unroll
  for (int mi = 0; mi < 4; ++mi)
#pragma unroll
    for (int ni = 0; ni < 4; ++ni) acc[mi][ni] = 0.0f;

  ushort8 g0, g3;
  auto LOAD_A = [&](int ch) {
    const size_t base = (size_t)(gm0 + ar) * 256 + ch * 64 + ac * 8;
    g0 = *(const ushort8*)&y1[base];
    g3 = *(const ushort8*)&y1[base + (size_t)64 * 256];
  };
  auto PROC_A = [&](int ch, int dst) {
    const int k0 = ch * 64 + ac * 8;
    ushort8 oa, ob;
#pragma unroll
    for (int j = 0; j < 8; ++j) {
      const float a = sSt[k0 + j], cc = sSt[256 + k0 + j];
      oa[j] = f2b(fmaxf(fmaf(b2f(g0[j]), a, cc), 0.0f));
      ob[j] = f2b(fmaxf(fmaf(b2f(g3[j]), a, cc), 0.0f));
    }
    *(ushort8*)&As[dst][ar * 72 + ac * 8] = oa;
    *(ushort8*)&As[dst][rb2 * 72 + ac * 8] = ob;
  };
  auto STAGE_B = [&](int ch) {
    const int kbase = ch * 64;
#pragma unroll
    for (int i = 0; i < 4; ++i) {
      const int fc = i * 512 + tid;
      const int row = fc >> 3, p = fc & 7;
      const int cc = p ^ (row & 7);
      gl_lds16(&Wb[(size_t)row * 256 + kbase + cc * 8], &Bs[i * 4096 + wv * 512]);
    }
  };
  auto COMPUTE = [&](int src) {
#pragma unroll
    for (int ks = 0; ks < 2; ++ks) {
      ushort8 af[4], bfr[4];
#pragma unroll
      for (int mi = 0; mi < 4; ++mi)
        af[mi] = *(const ushort8*)&As[src][(m0 + mi * 16 + la) * 72 + (ks * 4 + qg) * 8];
#pragma unroll
      for (int ni = 0; ni < 4; ++ni) {
        const int ro = o0 + ni * 16 + la;
        bfr[ni] = *(const ushort8*)&Bs[ro * 64 + (((ks * 4 + qg) ^ (ro & 7))) * 8];
      }
#pragma unroll
      for (int mi = 0; mi < 4; ++mi)
#pragma unroll
        for (int ni = 0; ni < 4; ++ni)
          acc[mi][ni] = mfma16(af[mi], bfr[ni], acc[mi][ni]);
    }
  };

  STAGE_B(0); LOAD_A(0); PROC_A(0, 0);
  __syncthreads();
  int buf = 0;
  for (int ch = 0; ch < 4; ++ch) {
    if (ch < 3) LOAD_A(ch + 1);
    COMPUTE(buf);
    __syncthreads();
    if (ch < 3) { STAGE_B(ch + 1); PROC_A(ch + 1, buf ^ 1); __syncthreads(); buf ^= 1; }
  }

#pragma unroll
  for (int mi = 0; mi < 4; ++mi)
#pragma unroll
    for (int ni = 0; ni < 4; ++ni) {
      const int oc = o0 + ni * 16 + la;
#pragma unroll
      for (int r = 0; r < 4; ++r) {
        const int m = gm0 + m0 + mi * 16 + qg * 4 + r;
        y1[(size_t)m * 256 + oc] = f2b(acc[mi][ni][r]);
      }
    }
#pragma unroll
  for (int ni = 0; ni < 4; ++ni) {
    float s = 0.f, qq = 0.f;
#pragma unroll
    for (int mi = 0; mi < 4; ++mi)
#pragma unroll
      for (int r = 0; r < 4; ++r) {
        const float v = acc[mi][ni][r];
        s += v; qq = fmaf(v, v, qq);
      }
    s += __shfl_xor(s, 16); s += __shfl_xor(s, 32);
    qq += __shfl_xor(qq, 16); qq += __shfl_xor(qq, 32);
    if (lane < 16) {
      sRedS[wm * 256 + o0 + ni * 16 + lane] = s;
      sRedQ[wm * 256 + o0 + ni * 16 + lane] = qq;
    }
  }
  __syncthreads();
  if (tid < 256) {
    part[(size_t)blockIdx.x * 512 + tid] = sRedS[tid] + sRedS[256 + tid];
    part[(size_t)blockIdx.x * 512 + 256 + tid] = sRedQ[tid] + sRedQ[256 + tid];
  }
}

// ---------------- final: BN+ReLU + transpose y2[m][o] -> out[b][o][n] (f32) --------
__global__ __launch_bounds__(256) void k_final(const ushort_t* __restrict__ y2,
                                               const float* __restrict__ st2,
                                               float* __restrict__ out) {
  __shared__ __align__(16) ushort_t tile[64 * 264];
  const int t = threadIdx.x;
  const int n0 = blockIdx.x * 64;
  const int b = blockIdx.y;
#pragma unroll
  for (int r = 0; r < 8; ++r) {
    const int id = r * 256 + t;
    const int row = id >> 5, c8 = id & 31;
    *(ushort8*)&tile[row * 264 + c8 * 8] =
        *(const ushort8*)&y2[((size_t)b * N2_ + n0 + row) * 256 + c8 * 8];
  }
  __syncthreads();
#pragma unroll
  for (int r = 0; r < 16; ++r) {
    const int id = r * 256 + t;
    const int o = id >> 4, nq = id & 15;
    const float a = st2[o], c = st2[256 + o];
    float4 v;
    v.x = fmaxf(fmaf(b2f(tile[(nq * 4 + 0) * 264 + o]), a, c), 0.0f);
    v.y = fmaxf(fmaf(b2f(tile[(nq * 4 + 1) * 264 + o]), a, c), 0.0f);
    v.z = fmaxf(fmaf(b2f(tile[(nq * 4 + 2) * 264 + o]), a, c), 0.0f);
    v.w = fmaxf(fmaf(b2f(tile[(nq * 4 + 3) * 264 + o]), a, c), 0.0f);
    *(float4*)&out[((size_t)b * 256 + o) * N2_ + n0 + nq * 4] = v;
  }
}

extern "C" void kernel_launch(void* const* d_in, const int* in_sizes, int n_in,
                              void* d_out, int out_size, void* d_ws, size_t ws_size,
                              hipStream_t stream) {
  (void)in_sizes; (void)n_in; (void)out_size; (void)ws_size;
  const float* xyz2  = (const float*)d_in[0];
  const float* xyz1  = (const float*)d_in[1];
  const float* feat2 = (const float*)d_in[2];
  const float* feat1 = (const float*)d_in[3];
  const float* W1  = (const float*)d_in[4];
  const float* g1  = (const float*)d_in[6];
  const float* be1 = (const float*)d_in[7];
  const float* W2  = (const float*)d_in[8];
  const float* g2  = (const float*)d_in[10];
  const float* be2 = (const float*)d_in[11];
  float* out = (float*)d_out;

  char* ws = (char*)d_ws;
  // y1 (33.5MB) overlays f1tb (8.4MB): f1tb dead before gemm1 writes y1
  ushort_t* y1    = (ushort_t*)(ws);               // 33,554,432
  ushort_t* f1tb  = (ushort_t*)(ws);               //  8,388,608 (prep/nn3 only)
  ushort_t* xcat  = (ushort_t*)(ws + 33554432);    // 50,331,648
  ushort_t* W1b   = (ushort_t*)(ws + 83886080);    //    196,608
  ushort_t* W2b   = (ushort_t*)(ws + 84082688);    //    131,072
  float*    part1 = (float*)(ws + 84213760);       //  1,048,576
  float*    part2 = (float*)(ws + 85262336);       //  1,048,576
  float*    st1   = (float*)(ws + 86310912);       //      2,048
  float*    st2   = (float*)(ws + 86312960);       //      2,048
  float*    sxg   = (float*)(ws + 86315008);       //     65,536
  float*    syg   = (float*)(ws + 86380544);       //     65,536
  float*    szg   = (float*)(ws + 86446080);       //     65,536
  unsigned* siog  = (unsigned*)(ws + 86511616);    //     65,536
  int*      gridg = (int*)(ws + 86577152);         //      8,224

  k_prep<<<4264, 256, 0, stream>>>(feat1, f1tb, xyz1, sxg, syg, szg, siog, gridg,
                                   W1, W2, W1b, W2b);
  k_nn3<<<10240, 256, 0, stream>>>(xyz2, sxg, syg, szg, siog, gridg, f1tb, xcat, feat2);
  k_gemm1<<<512, 512, 0, stream>>>(xcat, W1b, y1, part1);
  k_reduce<<<256, 256, 0, stream>>>(part1, g1, be1, st1);
  k_gemm2<<<512, 512, 0, stream>>>(y1, W2b, st1, part2);
  k_reduce<<<256, 256, 0, stream>>>(part2, g2, be2, st2);
  k_final<<<dim3(128, 8), 256, 0, stream>>>(y1, st2, out);
}